// Round 5
// baseline (5120.806 us; speedup 1.0000x reference)
//
#include <hip/hip_runtime.h>
#include <hip/hip_bf16.h>
#include <stdint.h>

// Problem constants (fixed by reference)
#define TSEQ   2048
#define DMODEL 1024
#define NH     16
#define HDIM   64
#define NKVH   4

typedef __attribute__((ext_vector_type(4))) float f32x4;

// ---- fp32 SIMT GEMM: C[M,N] = A[M,K] @ B[K,N] + bias[N]
// block 256 threads, 64x64 tile, 4x4 outputs/thread, K-step 16.
// (validated: rounds 2 & 3 agree through two independent implementations)
__global__ __launch_bounds__(256) void sgemm_bias(
    const float* __restrict__ A, const float* __restrict__ B,
    const float* __restrict__ bias, float* __restrict__ Cf,
    int M, int N, int K)
{
    __shared__ float As[64][20];   // [m][k], padded row stride 20
    __shared__ float Bs[16][64];   // [k][n]
    const int tid = threadIdx.x;
    const int tx = tid & 15, ty = tid >> 4;
    const int m0 = blockIdx.y * 64, n0 = blockIdx.x * 64;
    f32x4 acc[4];
#pragma unroll
    for (int r = 0; r < 4; ++r) acc[r] = (f32x4){0.f, 0.f, 0.f, 0.f};

    const int ar = tid >> 2, ac = (tid & 3) * 4;     // A: 64 rows x 16 k
    const int br = tid >> 4, bc = (tid & 15) * 4;    // B: 16 rows x 64 n

    for (int k0 = 0; k0 < K; k0 += 16) {
        __syncthreads();
        f32x4 a4 = *(const f32x4*)(A + (size_t)(m0 + ar) * K + k0 + ac);
        *(f32x4*)(&As[ar][ac]) = a4;
        f32x4 b4 = *(const f32x4*)(B + (size_t)(k0 + br) * N + n0 + bc);
        *(f32x4*)(&Bs[br][bc]) = b4;
        __syncthreads();
#pragma unroll
        for (int k4 = 0; k4 < 4; ++k4) {
            f32x4 av[4], bv[4];
#pragma unroll
            for (int r = 0; r < 4; ++r) av[r] = *(const f32x4*)(&As[ty * 4 + r][k4 * 4]);
#pragma unroll
            for (int kk = 0; kk < 4; ++kk) bv[kk] = *(const f32x4*)(&Bs[k4 * 4 + kk][tx * 4]);
#pragma unroll
            for (int kk = 0; kk < 4; ++kk)
#pragma unroll
                for (int r = 0; r < 4; ++r)
                    acc[r] += bv[kk] * av[r][kk];
        }
    }
#pragma unroll
    for (int r = 0; r < 4; ++r) {
        int row = m0 + ty * 4 + r;
#pragma unroll
        for (int c = 0; c < 4; ++c) {
            int col = n0 + tx * 4 + c;
            Cf[(size_t)row * N + col] = acc[r][c] + bias[col];
        }
    }
}

// ---- RMSNorm q (in place) and k; emit plain fp32 K (kvh, t, d) and fp32 V ----
__global__ __launch_bounds__(256) void norm_kernel(
    float* __restrict__ qbuf, const float* __restrict__ kvbuf,
    const float* __restrict__ qn_w, const float* __restrict__ kn_w,
    float* __restrict__ kn, float* __restrict__ vbuf)
{
    const int t = blockIdx.x;
    const int tid = threadIdx.x;
#pragma unroll
    for (int it = 0; it < 6; ++it) {
        int idx = it * 256 + tid;
        int chunk = idx >> 6;        // 0..15 q heads, 16..19 k kvh, 20..23 v kvh
        int d = idx & 63;            // == lane; each wave handles exactly one chunk
        float val;
        if (chunk < 16)      val = qbuf[(size_t)t * DMODEL + chunk * 64 + d];
        else if (chunk < 20) val = kvbuf[(size_t)t * 512 + (chunk - 16) * 64 + d];
        else                 val = kvbuf[(size_t)t * 512 + 256 + (chunk - 20) * 64 + d];
        if (chunk < 20) {
            float ss = val * val;
#pragma unroll
            for (int j = 32; j > 0; j >>= 1) ss += __shfl_xor(ss, j, 64);
            float rs = 1.0f / sqrtf(ss * (1.0f / 64.0f) + 1e-8f);
            if (chunk < 16) {
                qbuf[(size_t)t * DMODEL + chunk * 64 + d] = val * rs * qn_w[d];
            } else {
                int kvh = chunk - 16;
                kn[((size_t)kvh * TSEQ + t) * HDIM + d] = val * rs * kn_w[d];
            }
        } else {
            int kvh = chunk - 20;
            vbuf[((size_t)kvh * TSEQ + t) * HDIM + d] = val;
        }
    }
}

// ---- fused score + exact top-64 (serial insertion) + softmax + V gather ----
// one wave per (h, t). Chunks of 64 keys processed from most-recent downward;
// within a chunk lane i scores key jb+i; lane 0 then inserts the 64 scores
// (descending j) into a priority-descending 64-entry list in LDS.
// Tie-break: iterating j descending, a new element (lower j) must rank ABOVE
// existing equal scores -> gate (s >= kept[63]) and insert-above-equals.
// This exactly matches jax.lax.top_k (ties -> lowest index first).
__global__ __launch_bounds__(512) void attn_kernel(
    const float* __restrict__ qn, const float* __restrict__ kn,
    const float* __restrict__ vbuf, float* __restrict__ ybuf)
{
    __shared__ float qs[8][64];    // q row per wave
    __shared__ float chs[8][64];   // current chunk scores
    __shared__ float ks[8][64];    // kept scores, priority-descending
    __shared__ int   ki[8][64];    // kept indices
    const int tid = threadIdx.x;
    const int wsid = tid >> 6, lane = tid & 63;
    const int h = blockIdx.x >> 8;
    const int t = ((blockIdx.x & 255) << 3) + wsid;
    const int kvh = h >> 2;
    const float slope = exp2f(-(((float)h / 15.0f) * 8.0f));

    qs[wsid][lane] = qn[(size_t)t * DMODEL + h * 64 + lane];
    ks[wsid][lane] = -1e30f;
    ki[wsid][lane] = 0;

    const float* kb = kn + (size_t)kvh * TSEQ * HDIM;
    const int nch = t >> 6;
    for (int c = nch; c >= 0; --c) {
        const int jb = c << 6;
        const int j = jb + lane;
        float s = -1e30f;
        if (j <= t) {
            const float* kr = kb + (size_t)j * HDIM;
            float a0 = 0.f, a1 = 0.f, a2 = 0.f, a3 = 0.f;
#pragma unroll
            for (int d4 = 0; d4 < 16; ++d4) {
                f32x4 k4 = *(const f32x4*)(kr + d4 * 4);
                f32x4 q4 = *(const f32x4*)(&qs[wsid][d4 * 4]);
                a0 += k4[0] * q4[0];
                a1 += k4[1] * q4[1];
                a2 += k4[2] * q4[2];
                a3 += k4[3] * q4[3];
            }
            s = ((a0 + a1) + (a2 + a3)) * 0.125f - slope * (float)(t - j);
        }
        chs[wsid][lane] = s;
        if (lane == 0) {
            for (int i = 63; i >= 0; --i) {       // j descending within chunk
                float sv = chs[wsid][i];
                if (sv > -1e29f && sv >= ks[wsid][63]) {
                    int p = 63;
                    while (p > 0 && sv >= ks[wsid][p - 1]) --p;
                    for (int m = 63; m > p; --m) {
                        ks[wsid][m] = ks[wsid][m - 1];
                        ki[wsid][m] = ki[wsid][m - 1];
                    }
                    ks[wsid][p] = sv;
                    ki[wsid][p] = jb + i;
                }
            }
        }
    }
    // softmax over the kept 64 (pads -1e30 -> weight 0); max is ks[wsid][0]
    float cs = ks[wsid][lane];
    int   ci = ki[wsid][lane];
    float msx = ks[wsid][0];
    bool valid = cs > -1e29f;
    float p = valid ? __expf(cs - msx) : 0.f;
    float l = p;
#pragma unroll
    for (int j2 = 32; j2 > 0; j2 >>= 1) l += __shfl_xor(l, j2, 64);
    float wgt = p / l;
    int widx = valid ? ci : 0;
    // V gather via wave broadcast
    float acc = 0.f;
    const float* vb = vbuf + (size_t)kvh * TSEQ * HDIM + lane;
#pragma unroll 8
    for (int i = 0; i < 64; ++i) {
        float w = __shfl(wgt, i, 64);
        int  ix = __shfl(widx, i, 64);
        acc += w * vb[(size_t)ix * HDIM];
    }
    ybuf[(size_t)t * DMODEL + h * 64 + lane] = acc;
}

extern "C" void kernel_launch(void* const* d_in, const int* in_sizes, int n_in,
                              void* d_out, int out_size, void* d_ws, size_t ws_size,
                              hipStream_t stream)
{
    // d_in order: x, wq, bq, wkv, bkv, wo, bo, qn_w, kn_w  (all fp32)
    const float* x    = (const float*)d_in[0];
    const float* wq   = (const float*)d_in[1];
    const float* bq   = (const float*)d_in[2];
    const float* wkv  = (const float*)d_in[3];
    const float* bkv  = (const float*)d_in[4];
    const float* wo   = (const float*)d_in[5];
    const float* bo   = (const float*)d_in[6];
    const float* qn_w = (const float*)d_in[7];
    const float* kn_w = (const float*)d_in[8];
    char* ws = (char*)d_ws;
    // ws layout (24 MB): qbuf fp32 8M | kvbuf fp32 4M | kn fp32 2M | v fp32 2M | y fp32 8M
    float* qbuf  = (float*)(ws);
    float* kvbuf = (float*)(ws + ((size_t)8  << 20));
    float* kn    = (float*)(ws + ((size_t)12 << 20));
    float* vbuf  = (float*)(ws + ((size_t)14 << 20));
    float* ybuf  = (float*)(ws + ((size_t)16 << 20));
    float* out   = (float*)d_out;   // fp32 output — reference returns float32

    sgemm_bias<<<dim3(DMODEL / 64, TSEQ / 64), 256, 0, stream>>>(
        x, wq, bq, qbuf, TSEQ, DMODEL, DMODEL);
    sgemm_bias<<<dim3(512 / 64, TSEQ / 64), 256, 0, stream>>>(
        x, wkv, bkv, kvbuf, TSEQ, 512, DMODEL);
    norm_kernel<<<TSEQ, 256, 0, stream>>>(qbuf, kvbuf, qn_w, kn_w, kn, vbuf);
    attn_kernel<<<NH * (TSEQ / 8), 512, 0, stream>>>(qbuf, kn, vbuf, ybuf);
    sgemm_bias<<<dim3(DMODEL / 64, TSEQ / 64), 256, 0, stream>>>(
        ybuf, wo, bo, out, TSEQ, DMODEL, DMODEL);
}

// Round 6
// 1376.426 us; speedup vs baseline: 3.7204x; 3.7204x over previous
//
#include <hip/hip_runtime.h>
#include <hip/hip_bf16.h>
#include <stdint.h>

// Problem constants (fixed by reference)
#define TSEQ   2048
#define DMODEL 1024
#define NH     16
#define HDIM   64
#define NKVH   4

typedef __attribute__((ext_vector_type(4))) float f32x4;

// priority comparator: higher score wins; tie -> lower index wins (matches jax top_k)
__device__ __forceinline__ bool pgt(float as, int ai, float bs, int bi) {
    return (as > bs) || (as == bs && ai < bi);
}

// full bitonic sort across 64 lanes, ascending by priority
__device__ __forceinline__ void bsort(float& s, int& i, int lane) {
#pragma unroll
    for (int k = 2; k <= 64; k <<= 1) {
#pragma unroll
        for (int j = k >> 1; j > 0; j >>= 1) {
            float os = __shfl_xor(s, j, 64);
            int   oi = __shfl_xor(i, j, 64);
            bool lower = (lane & j) == 0;
            bool asc   = (lane & k) == 0;   // k=64 -> ascending everywhere
            bool wmin  = (lower == asc);
            bool takeo = (pgt(s, i, os, oi) == wmin);
            if (takeo) { s = os; i = oi; }
        }
    }
}

// bitonic -> ascending cleanup (6 stages)
__device__ __forceinline__ void bmerge(float& s, int& i, int lane) {
#pragma unroll
    for (int j = 32; j > 0; j >>= 1) {
        float os = __shfl_xor(s, j, 64);
        int   oi = __shfl_xor(i, j, 64);
        bool lower = (lane & j) == 0;
        bool takeo = (pgt(s, i, os, oi) == lower);
        if (takeo) { s = os; i = oi; }
    }
}

// ---- fp32 SIMT GEMM: C[M,N] = A[M,K] @ B[K,N] + bias[N]  (validated R5) ----
__global__ __launch_bounds__(256) void sgemm_bias(
    const float* __restrict__ A, const float* __restrict__ B,
    const float* __restrict__ bias, float* __restrict__ Cf,
    int M, int N, int K)
{
    __shared__ float As[64][20];   // [m][k], padded row stride 20
    __shared__ float Bs[16][64];   // [k][n]
    const int tid = threadIdx.x;
    const int tx = tid & 15, ty = tid >> 4;
    const int m0 = blockIdx.y * 64, n0 = blockIdx.x * 64;
    f32x4 acc[4];
#pragma unroll
    for (int r = 0; r < 4; ++r) acc[r] = (f32x4){0.f, 0.f, 0.f, 0.f};

    const int ar = tid >> 2, ac = (tid & 3) * 4;     // A: 64 rows x 16 k
    const int br = tid >> 4, bc = (tid & 15) * 4;    // B: 16 rows x 64 n

    for (int k0 = 0; k0 < K; k0 += 16) {
        __syncthreads();
        f32x4 a4 = *(const f32x4*)(A + (size_t)(m0 + ar) * K + k0 + ac);
        *(f32x4*)(&As[ar][ac]) = a4;
        f32x4 b4 = *(const f32x4*)(B + (size_t)(k0 + br) * N + n0 + bc);
        *(f32x4*)(&Bs[br][bc]) = b4;
        __syncthreads();
#pragma unroll
        for (int k4 = 0; k4 < 4; ++k4) {
            f32x4 av[4], bv[4];
#pragma unroll
            for (int r = 0; r < 4; ++r) av[r] = *(const f32x4*)(&As[ty * 4 + r][k4 * 4]);
#pragma unroll
            for (int kk = 0; kk < 4; ++kk) bv[kk] = *(const f32x4*)(&Bs[k4 * 4 + kk][tx * 4]);
#pragma unroll
            for (int kk = 0; kk < 4; ++kk)
#pragma unroll
                for (int r = 0; r < 4; ++r)
                    acc[r] += bv[kk] * av[r][kk];
        }
    }
#pragma unroll
    for (int r = 0; r < 4; ++r) {
        int row = m0 + ty * 4 + r;
#pragma unroll
        for (int c = 0; c < 4; ++c) {
            int col = n0 + tx * 4 + c;
            Cf[(size_t)row * N + col] = acc[r][c] + bias[col];
        }
    }
}

// ---- RMSNorm q (in place) and k; emit plain fp32 K (kvh, t, d) and fp32 V ----
// (validated R5)
__global__ __launch_bounds__(256) void norm_kernel(
    float* __restrict__ qbuf, const float* __restrict__ kvbuf,
    const float* __restrict__ qn_w, const float* __restrict__ kn_w,
    float* __restrict__ kn, float* __restrict__ vbuf)
{
    const int t = blockIdx.x;
    const int tid = threadIdx.x;
#pragma unroll
    for (int it = 0; it < 6; ++it) {
        int idx = it * 256 + tid;
        int chunk = idx >> 6;        // 0..15 q heads, 16..19 k kvh, 20..23 v kvh
        int d = idx & 63;            // == lane; each wave handles exactly one chunk
        float val;
        if (chunk < 16)      val = qbuf[(size_t)t * DMODEL + chunk * 64 + d];
        else if (chunk < 20) val = kvbuf[(size_t)t * 512 + (chunk - 16) * 64 + d];
        else                 val = kvbuf[(size_t)t * 512 + 256 + (chunk - 20) * 64 + d];
        if (chunk < 20) {
            float ss = val * val;
#pragma unroll
            for (int j = 32; j > 0; j >>= 1) ss += __shfl_xor(ss, j, 64);
            float rs = 1.0f / sqrtf(ss * (1.0f / 64.0f) + 1e-8f);
            if (chunk < 16) {
                qbuf[(size_t)t * DMODEL + chunk * 64 + d] = val * rs * qn_w[d];
            } else {
                int kvh = chunk - 16;
                kn[((size_t)kvh * TSEQ + t) * HDIM + d] = val * rs * kn_w[d];
            }
        } else {
            int kvh = chunk - 20;
            vbuf[((size_t)kvh * TSEQ + t) * HDIM + d] = val;
        }
    }
}

// ---- fused score + exact top-64 (wave-parallel bitonic) + softmax + V gather
// one wave per (h, t); 8 waves/block share one head and walk chunks in
// near-lockstep (L1 K reuse). Chunks most-recent-first: ALiBi decay means
// insertions are front-loaded, so distant chunks skip the merge via the
// __any(s >= min(kept)) gate. Score loop + epilogue numerics byte-identical
// to the R5-validated serial version; selection proven equivalent (R3==R4
// bit-identical outputs through two independent implementations).
__global__ __launch_bounds__(512) void attn_kernel(
    const float* __restrict__ qn, const float* __restrict__ kn,
    const float* __restrict__ vbuf, float* __restrict__ ybuf)
{
    __shared__ float qs[8][64];    // q row per wave (wave-private: no barrier needed)
    const int tid = threadIdx.x;
    const int wsid = tid >> 6, lane = tid & 63;
    const int h = blockIdx.x >> 8;
    const int t = ((blockIdx.x & 255) << 3) + wsid;
    const int kvh = h >> 2;
    const float slope = exp2f(-(((float)h / 15.0f) * 8.0f));

    qs[wsid][lane] = qn[(size_t)t * DMODEL + h * 64 + lane];

    const float* kb = kn + (size_t)kvh * TSEQ * HDIM;
    const int nch = t >> 6;
    float cs = -1e30f; int ci = 0;
    for (int c = nch; c >= 0; --c) {
        const int jb = c << 6;
        const int j = jb + lane;
        float s = -1e30f;
        if (j <= t) {
            const float* kr = kb + (size_t)j * HDIM;
            float a0 = 0.f, a1 = 0.f, a2 = 0.f, a3 = 0.f;
#pragma unroll
            for (int d4 = 0; d4 < 16; ++d4) {
                f32x4 k4 = *(const f32x4*)(kr + d4 * 4);
                f32x4 q4 = *(const f32x4*)(&qs[wsid][d4 * 4]);
                a0 += k4[0] * q4[0];
                a1 += k4[1] * q4[1];
                a2 += k4[2] * q4[2];
                a3 += k4[3] * q4[3];
            }
            s = ((a0 + a1) + (a2 + a3)) * 0.125f - slope * (float)(t - j);
        }
        if (c == nch) {
            cs = s; ci = j;
            bsort(cs, ci, lane);              // ascending kept set
        } else {
            float th = __shfl(cs, 0, 64);     // 64th-largest so far
            if (__any(s >= th)) {
                float nsv = s; int niv = j;
                bsort(nsv, niv, lane);
                float rsv = __shfl_xor(nsv, 63, 64);   // descending view
                int   riv = __shfl_xor(niv, 63, 64);
                if (pgt(rsv, riv, cs, ci)) { cs = rsv; ci = riv; }
                bmerge(cs, ci, lane);         // restore ascending
            }
        }
    }
    // softmax over kept 64 (pads -1e30 -> weight 0); max at lane 63
    float msx = __shfl(cs, 63, 64);
    bool valid = cs > -1e29f;
    float p = valid ? __expf(cs - msx) : 0.f;
    float l = p;
#pragma unroll
    for (int j2 = 32; j2 > 0; j2 >>= 1) l += __shfl_xor(l, j2, 64);
    float wgt = p / l;
    int widx = valid ? ci : 0;
    // V gather via wave broadcast
    float acc = 0.f;
    const float* vb = vbuf + (size_t)kvh * TSEQ * HDIM + lane;
#pragma unroll 8
    for (int i = 0; i < 64; ++i) {
        float w = __shfl(wgt, i, 64);
        int  ix = __shfl(widx, i, 64);
        acc += w * vb[(size_t)ix * HDIM];
    }
    ybuf[(size_t)t * DMODEL + h * 64 + lane] = acc;
}

extern "C" void kernel_launch(void* const* d_in, const int* in_sizes, int n_in,
                              void* d_out, int out_size, void* d_ws, size_t ws_size,
                              hipStream_t stream)
{
    // d_in order: x, wq, bq, wkv, bkv, wo, bo, qn_w, kn_w  (all fp32)
    const float* x    = (const float*)d_in[0];
    const float* wq   = (const float*)d_in[1];
    const float* bq   = (const float*)d_in[2];
    const float* wkv  = (const float*)d_in[3];
    const float* bkv  = (const float*)d_in[4];
    const float* wo   = (const float*)d_in[5];
    const float* bo   = (const float*)d_in[6];
    const float* qn_w = (const float*)d_in[7];
    const float* kn_w = (const float*)d_in[8];
    char* ws = (char*)d_ws;
    // ws layout (24 MB): qbuf fp32 8M | kvbuf fp32 4M | kn fp32 2M | v fp32 2M | y fp32 8M
    float* qbuf  = (float*)(ws);
    float* kvbuf = (float*)(ws + ((size_t)8  << 20));
    float* kn    = (float*)(ws + ((size_t)12 << 20));
    float* vbuf  = (float*)(ws + ((size_t)14 << 20));
    float* ybuf  = (float*)(ws + ((size_t)16 << 20));
    float* out   = (float*)d_out;   // fp32 output — reference returns float32

    sgemm_bias<<<dim3(DMODEL / 64, TSEQ / 64), 256, 0, stream>>>(
        x, wq, bq, qbuf, TSEQ, DMODEL, DMODEL);
    sgemm_bias<<<dim3(512 / 64, TSEQ / 64), 256, 0, stream>>>(
        x, wkv, bkv, kvbuf, TSEQ, 512, DMODEL);
    norm_kernel<<<TSEQ, 256, 0, stream>>>(qbuf, kvbuf, qn_w, kn_w, kn, vbuf);
    attn_kernel<<<NH * (TSEQ / 8), 512, 0, stream>>>(qbuf, kn, vbuf, ybuf);
    sgemm_bias<<<dim3(DMODEL / 64, TSEQ / 64), 256, 0, stream>>>(
        ybuf, wo, bo, out, TSEQ, DMODEL, DMODEL);
}

// Round 7
// 461.923 us; speedup vs baseline: 11.0858x; 2.9798x over previous
//
#include <hip/hip_runtime.h>
#include <hip/hip_bf16.h>
#include <stdint.h>

// Problem constants (fixed by reference)
#define TSEQ   2048
#define DMODEL 1024
#define NH     16
#define HDIM   64
#define NKVH   4

typedef __attribute__((ext_vector_type(8))) short short8;
typedef __attribute__((ext_vector_type(4))) float f32x4;
typedef __hip_bfloat16 bf16;

// priority comparator: higher score wins; tie -> lower index wins (matches jax top_k)
__device__ __forceinline__ bool pgt(float as, int ai, float bs, int bi) {
    return (as > bs) || (as == bs && ai < bi);
}

// full bitonic sort across 64 lanes, ascending by priority (validated R6)
__device__ __forceinline__ void bsort(float& s, int& i, int lane) {
#pragma unroll
    for (int k = 2; k <= 64; k <<= 1) {
#pragma unroll
        for (int j = k >> 1; j > 0; j >>= 1) {
            float os = __shfl_xor(s, j, 64);
            int   oi = __shfl_xor(i, j, 64);
            bool lower = (lane & j) == 0;
            bool asc   = (lane & k) == 0;
            bool wmin  = (lower == asc);
            bool takeo = (pgt(s, i, os, oi) == wmin);
            if (takeo) { s = os; i = oi; }
        }
    }
}

// bitonic -> ascending cleanup (6 stages) (validated R6)
__device__ __forceinline__ void bmerge(float& s, int& i, int lane) {
#pragma unroll
    for (int j = 32; j > 0; j >>= 1) {
        float os = __shfl_xor(s, j, 64);
        int   oi = __shfl_xor(i, j, 64);
        bool lower = (lane & j) == 0;
        bool takeo = (pgt(s, i, os, oi) == lower);
        if (takeo) { s = os; i = oi; }
    }
}

// ---- fp32 -> bf16 conversion of x, wq, wkv, wo ----
__global__ __launch_bounds__(256) void convert_bf16(
    const float* __restrict__ x, const float* __restrict__ wq,
    const float* __restrict__ wkv, const float* __restrict__ wo,
    bf16* __restrict__ cx, bf16* __restrict__ cwq,
    bf16* __restrict__ cwkv, bf16* __restrict__ cwo)
{
    const size_t i0 = (size_t)blockIdx.x * 256 + threadIdx.x;
    const size_t stride = (size_t)gridDim.x * 256;
    for (size_t i = i0; i < 2097152; i += stride) cx[i]   = __float2bfloat16(x[i]);
    for (size_t i = i0; i < 1048576; i += stride) cwq[i]  = __float2bfloat16(wq[i]);
    for (size_t i = i0; i < 524288;  i += stride) cwkv[i] = __float2bfloat16(wkv[i]);
    for (size_t i = i0; i < 1048576; i += stride) cwo[i]  = __float2bfloat16(wo[i]);
}

// ---- MFMA GEMM: C[M,N] fp32 = A[M,K](bf16) @ B[K,N](bf16) + bias[N](fp32)
// 64x64 tile, 4 waves, mfma 16x16x32. (R2 code — validated to bf16 precision
// by R2==R3 bit-identical outputs.)
__global__ __launch_bounds__(256) void gemm_bias(
    const bf16* __restrict__ A, const bf16* __restrict__ B,
    const float* __restrict__ bias, float* __restrict__ C,
    int M, int N, int K)
{
    __shared__ short As[64][32];   // (m, k)
    __shared__ short Bt[64][32];   // (n, k)
    const int tid = threadIdx.x;
    const int m0 = blockIdx.y * 64, n0 = blockIdx.x * 64;
    const int w = tid >> 6, lane = tid & 63;
    const int q = lane >> 4, mm = lane & 15;
    f32x4 acc[4];
#pragma unroll
    for (int nb = 0; nb < 4; ++nb) acc[nb] = (f32x4){0.f, 0.f, 0.f, 0.f};
    const int arow = tid >> 2, akc = (tid & 3) * 8;
    const int brow = tid >> 3, bnc = (tid & 7) * 8;
    const short* Ag = (const short*)A;
    const short* Bg = (const short*)B;
    for (int k0 = 0; k0 < K; k0 += 32) {
        __syncthreads();
        short8 av = *(const short8*)(Ag + (size_t)(m0 + arow) * K + k0 + akc);
        *(short8*)(&As[arow][akc]) = av;
        short8 bv = *(const short8*)(Bg + (size_t)(k0 + brow) * N + n0 + bnc);
#pragma unroll
        for (int jj = 0; jj < 8; ++jj) Bt[bnc + jj][brow] = bv[jj];
        __syncthreads();
        short8 af = *(const short8*)(&As[w * 16 + mm][q * 8]);
#pragma unroll
        for (int nb = 0; nb < 4; ++nb) {
            short8 bfr = *(const short8*)(&Bt[nb * 16 + mm][q * 8]);
            acc[nb] = __builtin_amdgcn_mfma_f32_16x16x32_bf16(af, bfr, acc[nb], 0, 0, 0);
        }
    }
#pragma unroll
    for (int nb = 0; nb < 4; ++nb) {
#pragma unroll
        for (int r = 0; r < 4; ++r) {
            int row = m0 + w * 16 + q * 4 + r;
            int col = n0 + nb * 16 + mm;
            C[(size_t)row * N + col] = acc[nb][r] + bias[col];
        }
    }
}

// ---- RMSNorm q (in place, fp32) and k; emit packed-bf16 K^T and fp32 V ----
// kT2 layout: (kvh, dpair=32, t=2048) u32 = {bf16 d=2dp (lo), d=2dp+1 (hi)}
__global__ __launch_bounds__(256) void norm_kernel(
    float* __restrict__ qbuf, const float* __restrict__ kvbuf,
    const float* __restrict__ qn_w, const float* __restrict__ kn_w,
    uint32_t* __restrict__ kT2, float* __restrict__ vbuf)
{
    const int t = blockIdx.x;
    const int tid = threadIdx.x;
#pragma unroll
    for (int it = 0; it < 6; ++it) {
        int idx = it * 256 + tid;
        int chunk = idx >> 6;        // 0..15 q heads, 16..19 k kvh, 20..23 v kvh
        int d = idx & 63;
        float val;
        if (chunk < 16)      val = qbuf[(size_t)t * DMODEL + chunk * 64 + d];
        else if (chunk < 20) val = kvbuf[(size_t)t * 512 + (chunk - 16) * 64 + d];
        else                 val = kvbuf[(size_t)t * 512 + 256 + (chunk - 20) * 64 + d];
        if (chunk < 20) {
            float ss = val * val;
#pragma unroll
            for (int j = 32; j > 0; j >>= 1) ss += __shfl_xor(ss, j, 64);
            float rs = 1.0f / sqrtf(ss * (1.0f / 64.0f) + 1e-8f);
            if (chunk < 16) {
                qbuf[(size_t)t * DMODEL + chunk * 64 + d] = val * rs * qn_w[d];
            } else {
                int kvh = chunk - 16;
                bf16 kb = __float2bfloat16(val * rs * kn_w[d]);
                unsigned short us; __builtin_memcpy(&us, &kb, 2);
                int ob = __shfl_xor((int)us, 1, 64);
                if ((d & 1) == 0) {
                    uint32_t u = ((uint32_t)(unsigned short)ob << 16) | (uint32_t)us;
                    kT2[((size_t)kvh * 32 + (d >> 1)) * TSEQ + t] = u;
                }
            }
        } else {
            int kvh = chunk - 20;
            vbuf[((size_t)(kvh) * TSEQ + t) * HDIM + d] = val;
        }
    }
}

// ---- fused score + exact top-64 bitonic + softmax + V gather ----
// one wave per (h, t). K loads are coalesced (t-contiguous packed bf16);
// q broadcast into registers once per wave. Chunks most-recent-first so the
// __any(s >= min(kept)) gate skips merges for distant chunks.
__global__ __launch_bounds__(512) void attn_kernel(
    const float* __restrict__ qn, const uint32_t* __restrict__ kT2,
    const float* __restrict__ vbuf, bf16* __restrict__ ybuf)
{
    const int tid = threadIdx.x;
    const int wsid = tid >> 6, lane = tid & 63;
    const int h = blockIdx.x >> 8;
    const int t = ((blockIdx.x & 255) << 3) + wsid;
    const int kvh = h >> 2;
    const float slope = exp2f(-(((float)h / 15.0f) * 8.0f));

    // q premultiplied by scale=1/8 (exact pow2); broadcast to all lanes once
    float qv = qn[(size_t)t * DMODEL + h * 64 + lane] * 0.125f;
    float qb[64];
#pragma unroll
    for (int d = 0; d < 64; ++d) qb[d] = __shfl(qv, d, 64);

    const uint32_t* kp = kT2 + (size_t)kvh * 32 * TSEQ;
    const int nch = t >> 6;
    float cs = -1e30f; int ci = 0;
    for (int c = nch; c >= 0; --c) {
        const int jb = c << 6;
        const int j = jb + lane;
        uint32_t ku[32];
#pragma unroll
        for (int dp = 0; dp < 32; ++dp) ku[dp] = kp[(size_t)dp * TSEQ + jb + lane];
        float s = 0.f;
#pragma unroll
        for (int dp = 0; dp < 32; ++dp) {
            float lo = __uint_as_float(ku[dp] << 16);
            float hi = __uint_as_float(ku[dp] & 0xffff0000u);
            s += lo * qb[2 * dp] + hi * qb[2 * dp + 1];
        }
        s = (j <= t) ? (s - slope * (float)(t - j)) : -1e30f;
        if (c == nch) {
            cs = s; ci = j;
            bsort(cs, ci, lane);              // ascending kept set
        } else {
            float th = __shfl(cs, 0, 64);     // 64th-largest so far
            if (__any(s >= th)) {
                float nsv = s; int niv = j;
                bsort(nsv, niv, lane);
                float rsv = __shfl_xor(nsv, 63, 64);   // descending view
                int   riv = __shfl_xor(niv, 63, 64);
                if (pgt(rsv, riv, cs, ci)) { cs = rsv; ci = riv; }
                bmerge(cs, ci, lane);         // restore ascending
            }
        }
    }
    // softmax over kept 64 (pads -1e30 -> weight 0); max at lane 63
    float msx = __shfl(cs, 63, 64);
    bool valid = cs > -1e29f;
    float p = valid ? __expf(cs - msx) : 0.f;
    float l = p;
#pragma unroll
    for (int j2 = 32; j2 > 0; j2 >>= 1) l += __shfl_xor(l, j2, 64);
    float wgt = p / l;
    int widx = valid ? ci : 0;
    // V gather via wave broadcast (coalesced: fixed i -> consecutive lanes)
    float acc = 0.f;
    const float* vb = vbuf + (size_t)kvh * TSEQ * HDIM + lane;
#pragma unroll 8
    for (int i = 0; i < 64; ++i) {
        float w = __shfl(wgt, i, 64);
        int  ix = __shfl(widx, i, 64);
        acc += w * vb[(size_t)ix * HDIM];
    }
    ybuf[(size_t)t * DMODEL + h * 64 + lane] = __float2bfloat16(acc);
}

extern "C" void kernel_launch(void* const* d_in, const int* in_sizes, int n_in,
                              void* d_out, int out_size, void* d_ws, size_t ws_size,
                              hipStream_t stream)
{
    // d_in order: x, wq, bq, wkv, bkv, wo, bo, qn_w, kn_w  (all fp32)
    const float* x    = (const float*)d_in[0];
    const float* wq   = (const float*)d_in[1];
    const float* bq   = (const float*)d_in[2];
    const float* wkv  = (const float*)d_in[3];
    const float* bkv  = (const float*)d_in[4];
    const float* wo   = (const float*)d_in[5];
    const float* bo   = (const float*)d_in[6];
    const float* qn_w = (const float*)d_in[7];
    const float* kn_w = (const float*)d_in[8];
    char* ws = (char*)d_ws;
    // ws layout (28 MB):
    // cx bf16 4M @0 | cwq bf16 2M @4M | cwkv bf16 1M @6M | cwo bf16 2M @7M |
    // qbuf fp32 8M @9M | kvbuf fp32 4M @17M | kT2 u32 1M @21M |
    // vbuf fp32 2M @22M | ybuf bf16 4M @24M
    bf16*     cx    = (bf16*)(ws);
    bf16*     cwq   = (bf16*)(ws + ((size_t)4  << 20));
    bf16*     cwkv  = (bf16*)(ws + ((size_t)6  << 20));
    bf16*     cwo   = (bf16*)(ws + ((size_t)7  << 20));
    float*    qbuf  = (float*)(ws + ((size_t)9  << 20));
    float*    kvbuf = (float*)(ws + ((size_t)17 << 20));
    uint32_t* kT2   = (uint32_t*)(ws + ((size_t)21 << 20));
    float*    vbuf  = (float*)(ws + ((size_t)22 << 20));
    bf16*     ybuf  = (bf16*)(ws + ((size_t)24 << 20));
    float*    out   = (float*)d_out;   // fp32 output

    convert_bf16<<<2048, 256, 0, stream>>>(x, wq, wkv, wo, cx, cwq, cwkv, cwo);
    gemm_bias<<<dim3(DMODEL / 64, TSEQ / 64), 256, 0, stream>>>(
        cx, cwq, bq, qbuf, TSEQ, DMODEL, DMODEL);
    gemm_bias<<<dim3(512 / 64, TSEQ / 64), 256, 0, stream>>>(
        cx, cwkv, bkv, kvbuf, TSEQ, 512, DMODEL);
    norm_kernel<<<TSEQ, 256, 0, stream>>>(qbuf, kvbuf, qn_w, kn_w, kT2, vbuf);
    attn_kernel<<<NH * (TSEQ / 8), 512, 0, stream>>>(qbuf, kT2, vbuf, ybuf);
    gemm_bias<<<dim3(DMODEL / 64, TSEQ / 64), 256, 0, stream>>>(
        ybuf, cwo, bo, out, TSEQ, DMODEL, DMODEL);
}